// Round 11
// baseline (498.931 us; speedup 1.0000x reference)
//
#include <hip/hip_runtime.h>
#include <math.h>

#define N_    16
#define CIN_  16
#define T_    512
#define V_    200
#define K_    3
#define COUT_ 64
#define H_    64
#define G_    256  // 4*H

// Workspace layout (float offsets):
//   a  : [0, 600)                 a[k][v] = sum_w A[k,v,w] / V
//   sa : [640, 643)               sa[k] = sum_{v,w} A[k,v,w] / V
//   xa : [1024, 1024+16*512*48)   xa[n][t][k*16+ci]
//   xW : [WS_XW, +512*4*4*64*4)   xW fragments: [t][wave][type][lane] float4
#define WS_A  0
#define WS_SA 640
#define WS_XA 1024
#define WS_XW (WS_XA + N_ * T_ * K_ * CIN_)

typedef __attribute__((ext_vector_type(8))) short short8;
typedef __attribute__((ext_vector_type(4))) float f32x4;

// fast activations: v_exp_f32-based, ~1e-6 rel err, saturate correctly
__device__ __forceinline__ float fast_sig(float x) {
    return __builtin_amdgcn_rcpf(1.f + __expf(-x));
}
__device__ __forceinline__ float fast_tanh(float x) {
    return fmaf(-2.f, __builtin_amdgcn_rcpf(1.f + __expf(2.f * x)), 1.f);
}
// bf16 round-to-nearest-even split helpers (finite values only)
__device__ __forceinline__ unsigned short f2bf(float f) {
    unsigned u = __float_as_uint(f);
    u += 0x7FFFu + ((u >> 16) & 1u);
    return (unsigned short)(u >> 16);
}
__device__ __forceinline__ float bf2f(unsigned short s) {
    return __uint_as_float(((unsigned)s) << 16);
}

// ---------------------------------------------------------------------------
// Kernel 1 (fused prep): blocks [0, NCOPY) copy A->out[16:] (and blocks 0-2
// also compute a[k][v]); blocks NCOPY+k (k=0..2) reduce A[k] to sa[k].
#define NCOPY ((K_ * V_ * V_ + 255) / 256)
__global__ __launch_bounds__(256) void prep_kernel(const float* __restrict__ A,
                                                   float* __restrict__ out,
                                                   float* __restrict__ ws) {
    int b = blockIdx.x;
    if (b < NCOPY) {
        int tid = b * 256 + threadIdx.x;
        if (tid < K_ * V_ * V_) out[16 + tid] = A[tid];
        if (tid < K_ * V_) {
            const float* row = A + (long)tid * V_;
            float s = 0.f;
            for (int w = 0; w < V_; ++w) s += row[w];
            ws[WS_A + tid] = s * (1.0f / V_);
        }
    } else {
        int k = b - NCOPY;                      // 0..2
        const float* Ak = A + (long)k * V_ * V_;
        float s = 0.f;
        for (int i = threadIdx.x; i < V_ * V_; i += 256) s += Ak[i];
        #pragma unroll
        for (int m = 1; m < 64; m <<= 1) s += __shfl_xor(s, m);
        __shared__ float red[4];
        if ((threadIdx.x & 63) == 0) red[threadIdx.x >> 6] = s;
        __syncthreads();
        if (threadIdx.x == 0)
            ws[WS_SA + k] = (red[0] + red[1] + red[2] + red[3]) * (1.0f / V_);
    }
}

// ---------------------------------------------------------------------------
// Kernel 2 (tiled xa): xa[n][t][k*16+ci] = sum_v x[n][ci][t][v] * a[k][v]
#define TT 64
#define PADV 204
__global__ __launch_bounds__(256) void xa_kernel(const float* __restrict__ x,
                                                 float* __restrict__ ws) {
    __shared__ __align__(16) float xt[TT * PADV];
    __shared__ __align__(16) float aS[K_ * V_];
    int tid = threadIdx.x;
    int b = blockIdx.x;
    int tchunk = b & 7;
    int ci = (b >> 3) & 15;
    int n = b >> 7;
    int t0 = tchunk * TT;

    for (int i = tid; i < K_ * V_; i += 256) aS[i] = ws[WS_A + i];

    const float4* xg4 =
        (const float4*)(x + ((long)(n * CIN_ + ci) * T_ + t0) * V_);
    for (int j = tid; j < TT * (V_ / 4); j += 256) {
        float4 v = xg4[j];
        int t = j / (V_ / 4), v4 = (j % (V_ / 4)) * 4;
        *(float4*)(xt + t * PADV + v4) = v;
    }
    __syncthreads();

    int t_local = tid & 63;
    int k = tid >> 6;            // waves 0..2 active, wave 3 idle
    if (k < K_) {
        const float* xr = xt + t_local * PADV;
        const float* ar = aS + k * V_;
        float a0 = 0.f, a1 = 0.f, a2 = 0.f, a3 = 0.f;
        #pragma unroll 5
        for (int v4 = 0; v4 < V_; v4 += 4) {
            float4 xv = *(const float4*)(xr + v4);
            float4 av = *(const float4*)(ar + v4);   // wave-uniform broadcast
            a0 = fmaf(xv.x, av.x, a0);
            a1 = fmaf(xv.y, av.y, a1);
            a2 = fmaf(xv.z, av.z, a2);
            a3 = fmaf(xv.w, av.w, a3);
        }
        float s = (a0 + a1) + (a2 + a3);
        ws[WS_XA + ((long)n * T_ + (t0 + t_local)) * (K_ * CIN_) + k * CIN_ + ci] = s;
    }
}

// ---------------------------------------------------------------------------
// Kernel 3 (fused seq + input-gate GEMM): ONE block per t (512 blocks).
// Phase-2 now writes xW in MFMA C-fragment order: [t][wave][type][lane] f4,
// where n = 4*(lane>>4)+r, g = type*64 + 16*wave + (lane&15).
__global__ __launch_bounds__(256) void seqgates_kernel(
    const float* __restrict__ W_gcn, const float* __restrict__ b_gcn,
    const float* __restrict__ W_ih, const float* __restrict__ b_ih,
    const float* __restrict__ b_hh, float* __restrict__ ws) {
    int t = blockIdx.x;
    int tid = threadIdx.x;
    __shared__ float xaS[N_][K_ * CIN_];
    __shared__ __align__(16) float seqS[N_][COUT_];
    __shared__ float saS[K_];

    if (tid < K_) saS[tid] = ws[WS_SA + tid];
    #pragma unroll
    for (int r = 0; r < 3; ++r) {
        int i = tid + r * 256;
        if (i < N_ * K_ * CIN_) {
            int n = i / (K_ * CIN_), kc = i % (K_ * CIN_);
            xaS[n][kc] = ws[WS_XA + (long)(n * T_ + t) * (K_ * CIN_) + kc];
        }
    }
    __syncthreads();

    {
        int n = tid >> 4, c0 = (tid & 15) * 4;
        #pragma unroll
        for (int cc = 0; cc < 4; ++cc) {
            int c = c0 + cc;
            float s = 0.f;
            #pragma unroll
            for (int k = 0; k < K_; ++k) {
                s = fmaf(b_gcn[k * COUT_ + c], saS[k], s);
                const float* wrow = W_gcn + (long)(k * COUT_ + c) * CIN_;
                #pragma unroll
                for (int ci = 0; ci < CIN_; ++ci)
                    s = fmaf(wrow[ci], xaS[n][k * CIN_ + ci], s);
            }
            seqS[n][c] = s;
        }
    }
    __syncthreads();

    {
        int g = tid;
        float acc[N_];
        #pragma unroll
        for (int n = 0; n < N_; ++n) acc[n] = 0.f;
        const float4* wrow4 = (const float4*)(W_ih + (long)g * H_);
        #pragma unroll
        for (int c4 = 0; c4 < H_ / 4; ++c4) {
            float4 w4 = wrow4[c4];
            #pragma unroll
            for (int n = 0; n < N_; ++n) {
                float4 s4 = ((const float4*)seqS[n])[c4];  // LDS broadcast
                acc[n] = fmaf(w4.x, s4.x, acc[n]);
                acc[n] = fmaf(w4.y, s4.y, acc[n]);
                acc[n] = fmaf(w4.z, s4.z, acc[n]);
                acc[n] = fmaf(w4.w, s4.w, acc[n]);
            }
        }
        float bias = b_ih[g] + b_hh[g];
        int wv = (g >> 4) & 3, ty = g >> 6, col = g & 15;
        float4* xwf4 = (float4*)(ws + WS_XW);
        #pragma unroll
        for (int nb = 0; nb < 4; ++nb) {
            float4 o4;
            o4.x = acc[4 * nb + 0] + bias;
            o4.y = acc[4 * nb + 1] + bias;
            o4.z = acc[4 * nb + 2] + bias;
            o4.w = acc[4 * nb + 3] + bias;
            xwf4[(((long)t * 4 + wv) * 4 + ty) * 64 + nb * 16 + col] = o4;
        }
    }
}

// ---------------------------------------------------------------------------
// Kernel 4: LSTM scan via MFMA — ONE block, all 16 batches. Per step the
// recurrence is a 16x256x64 GEMM done as bf16 hi/lo split (3 products, fp32
// accumulate): W_hh lives permanently in 16 MFMA B-fragments (computed
// values -> not subject to the load-sinking pathology of R2-R7). Wave w owns
// gate-col slice [16w,16w+16); tile index = gate type, so each lane holds
// i,f,g,o for its 4 (n,j) cells in registers: no cross-lane exchange,
// 1 barrier/step (double-buffered h-as-A staging in LDS).
#define PADC 72
__global__ __launch_bounds__(256, 1) void lstm_kernel(
    const float* __restrict__ W_hh, const float* __restrict__ W_fc,
    const float* __restrict__ b_fc, const float* __restrict__ ws,
    float* __restrict__ out) {
    int tid = threadIdx.x;
    int w = tid >> 6;
    int l = tid & 63;
    int lg = l >> 4, ll = l & 15;

    // B-frags: B[k][col]=W_hh[g][c], g=ty*64+16w+ll, c = ks*32+8*lg+i
    short8 bhi[4][2], blo[4][2];
    #pragma unroll
    for (int ty = 0; ty < 4; ++ty) {
        #pragma unroll
        for (int ks = 0; ks < 2; ++ks) {
            const float* wp = W_hh + (long)(ty * 64 + 16 * w + ll) * H_ + ks * 32 + 8 * lg;
            short8 hi, lo;
            #pragma unroll
            for (int i = 0; i < 8; ++i) {
                float wv = wp[i];
                unsigned short hb = f2bf(wv);
                hi[i] = (short)hb;
                lo[i] = (short)f2bf(wv - bf2f(hb));
            }
            bhi[ty][ks] = hi;
            blo[ty][ks] = lo;
        }
    }
    #pragma unroll
    for (int ty = 0; ty < 4; ++ty)
        #pragma unroll
        for (int ks = 0; ks < 2; ++ks)
            asm volatile("" : "+v"(bhi[ty][ks]), "+v"(blo[ty][ks]));

    __shared__ __align__(16) unsigned short Ahi[2][16][PADC];
    __shared__ __align__(16) unsigned short Alo[2][16][PADC];
    __shared__ __align__(16) float hf[16][64];

    for (int i = tid; i < 16 * PADC; i += 256) {
        (&Ahi[0][0][0])[i] = 0;
        (&Alo[0][0][0])[i] = 0;
    }

    const f32x4* xwf = (const f32x4*)(ws + WS_XW);
    f32x4 xcur[4], xnxt[4];
    #pragma unroll
    for (int ty = 0; ty < 4; ++ty) xcur[ty] = xwf[((0 * 4 + w) * 4 + ty) * 64 + l];
    #pragma unroll
    for (int ty = 0; ty < 4; ++ty) xnxt[ty] = xwf[((1 * 4 + w) * 4 + ty) * 64 + l];

    float cst[4] = {0.f, 0.f, 0.f, 0.f};
    float hout[4] = {0.f, 0.f, 0.f, 0.f};
    __syncthreads();

    for (int t = 0; t < T_; ++t) {
        int p = t & 1;
        short8 ahi0 = *(const short8*)&Ahi[p][ll][0 * 32 + 8 * lg];
        short8 ahi1 = *(const short8*)&Ahi[p][ll][1 * 32 + 8 * lg];
        short8 alo0 = *(const short8*)&Alo[p][ll][0 * 32 + 8 * lg];
        short8 alo1 = *(const short8*)&Alo[p][ll][1 * 32 + 8 * lg];

        f32x4 acc[4];
        #pragma unroll
        for (int ty = 0; ty < 4; ++ty) {
            f32x4 a = xcur[ty];
            a = __builtin_amdgcn_mfma_f32_16x16x32_bf16(ahi0, bhi[ty][0], a, 0, 0, 0);
            a = __builtin_amdgcn_mfma_f32_16x16x32_bf16(ahi1, bhi[ty][1], a, 0, 0, 0);
            a = __builtin_amdgcn_mfma_f32_16x16x32_bf16(ahi0, blo[ty][0], a, 0, 0, 0);
            a = __builtin_amdgcn_mfma_f32_16x16x32_bf16(ahi1, blo[ty][1], a, 0, 0, 0);
            a = __builtin_amdgcn_mfma_f32_16x16x32_bf16(alo0, bhi[ty][0], a, 0, 0, 0);
            a = __builtin_amdgcn_mfma_f32_16x16x32_bf16(alo1, bhi[ty][1], a, 0, 0, 0);
            acc[ty] = a;
        }
        #pragma unroll
        for (int ty = 0; ty < 4; ++ty) xcur[ty] = xnxt[ty];
        if (t + 2 < T_) {
            #pragma unroll
            for (int ty = 0; ty < 4; ++ty)
                xnxt[ty] = xwf[(((long)(t + 2) * 4 + w) * 4 + ty) * 64 + l];
        }
        // lane owns (j = 16w+ll, n = 4*lg+r): i,f,g,o all local
        #pragma unroll
        for (int r = 0; r < 4; ++r) {
            float iv = fast_sig(acc[0][r]);
            float fv = fast_sig(acc[1][r]);
            float gv = fast_tanh(acc[2][r]);
            float ov = fast_sig(acc[3][r]);
            cst[r] = fmaf(fv, cst[r], iv * gv);
            hout[r] = ov * fast_tanh(cst[r]);
        }
        // pack h -> A[p^1]
        #pragma unroll
        for (int r = 0; r < 4; ++r) {
            int n = 4 * lg + r, j = 16 * w + ll;
            unsigned short hb = f2bf(hout[r]);
            Ahi[p ^ 1][n][j] = hb;
            Alo[p ^ 1][n][j] = f2bf(hout[r] - bf2f(hb));
        }
        __syncthreads();   // the ONLY barrier per step (dbuf makes it safe)
    }

    #pragma unroll
    for (int r = 0; r < 4; ++r) hf[4 * lg + r][16 * w + ll] = hout[r];
    __syncthreads();
    if (tid < N_) {
        float s = 0.f;
        for (int j = 0; j < H_; ++j) s = fmaf(hf[tid][j], W_fc[j], s);
        out[tid] = s + b_fc[0];
    }
}

// ---------------------------------------------------------------------------
extern "C" void kernel_launch(void* const* d_in, const int* in_sizes, int n_in,
                              void* d_out, int out_size, void* d_ws, size_t ws_size,
                              hipStream_t stream) {
    const float* x     = (const float*)d_in[0];
    const float* A     = (const float*)d_in[1];
    const float* W_gcn = (const float*)d_in[2];
    const float* b_gcn = (const float*)d_in[3];
    const float* W_ih  = (const float*)d_in[4];
    const float* W_hh  = (const float*)d_in[5];
    const float* b_ih  = (const float*)d_in[6];
    const float* b_hh  = (const float*)d_in[7];
    const float* W_fc  = (const float*)d_in[8];
    const float* b_fc  = (const float*)d_in[9];
    float* out = (float*)d_out;
    float* ws  = (float*)d_ws;

    // 1) fused: copy A->out, a[k][v], sa[k]
    prep_kernel<<<NCOPY + K_, 256, 0, stream>>>(A, out, ws);
    // 2) tiled xa (one block per (n, ci, 64-t chunk))
    xa_kernel<<<N_ * CIN_ * (T_ / TT), 256, 0, stream>>>(x, ws);
    // 3) fused seq + input-side gate GEMM (one block per t)
    seqgates_kernel<<<T_, 256, 0, stream>>>(W_gcn, b_gcn, W_ih, b_ih, b_hh, ws);
    // 4) MFMA LSTM scan (single block, all batches) + final FC
    lstm_kernel<<<1, 256, 0, stream>>>(W_hh, W_fc, b_fc, ws, out);
}

// Round 12
// 353.894 us; speedup vs baseline: 1.4098x; 1.4098x over previous
//
#include <hip/hip_runtime.h>
#include <math.h>

#define N_    16
#define CIN_  16
#define T_    512
#define V_    200
#define K_    3
#define COUT_ 64
#define H_    64
#define G_    256  // 4*H

// Workspace layout (float offsets):
//   a  : [0, 600)                 a[k][v] = sum_w A[k,v,w] / V
//   sa : [640, 643)               sa[k] = sum_{v,w} A[k,v,w] / V
//   xa : [1024, 1024+16*512*48)   xa[n][t][k*16+ci]
//   xW : [WS_XW, +512*16*256)     xW[t][n][g]  (gate pre-activations, input side)
#define WS_A  0
#define WS_SA 640
#define WS_XA 1024
#define WS_XW (WS_XA + N_ * T_ * K_ * CIN_)

typedef __attribute__((ext_vector_type(4))) float f32x4;

// fast activations: v_exp_f32-based, ~1e-6 rel err, saturate correctly
__device__ __forceinline__ float fast_sig(float x) {
    return __builtin_amdgcn_rcpf(1.f + __expf(-x));
}
__device__ __forceinline__ float fast_tanh(float x) {
    return fmaf(-2.f, __builtin_amdgcn_rcpf(1.f + __expf(2.f * x)), 1.f);
}

// ---------------------------------------------------------------------------
// Kernel 1 (fused prep): blocks [0, NCOPY) copy A->out[16:] (and blocks 0-2
// also compute a[k][v]); blocks NCOPY+k (k=0..2) reduce A[k] to sa[k].
#define NCOPY ((K_ * V_ * V_ + 255) / 256)
__global__ __launch_bounds__(256) void prep_kernel(const float* __restrict__ A,
                                                   float* __restrict__ out,
                                                   float* __restrict__ ws) {
    int b = blockIdx.x;
    if (b < NCOPY) {
        int tid = b * 256 + threadIdx.x;
        if (tid < K_ * V_ * V_) out[16 + tid] = A[tid];
        if (tid < K_ * V_) {
            const float* row = A + (long)tid * V_;
            float s = 0.f;
            for (int w = 0; w < V_; ++w) s += row[w];
            ws[WS_A + tid] = s * (1.0f / V_);
        }
    } else {
        int k = b - NCOPY;                      // 0..2
        const float* Ak = A + (long)k * V_ * V_;
        float s = 0.f;
        for (int i = threadIdx.x; i < V_ * V_; i += 256) s += Ak[i];
        #pragma unroll
        for (int m = 1; m < 64; m <<= 1) s += __shfl_xor(s, m);
        __shared__ float red[4];
        if ((threadIdx.x & 63) == 0) red[threadIdx.x >> 6] = s;
        __syncthreads();
        if (threadIdx.x == 0)
            ws[WS_SA + k] = (red[0] + red[1] + red[2] + red[3]) * (1.0f / V_);
    }
}

// ---------------------------------------------------------------------------
// Kernel 2 (tiled xa): xa[n][t][k*16+ci] = sum_v x[n][ci][t][v] * a[k][v]
#define TT 64
#define PADV 204
__global__ __launch_bounds__(256) void xa_kernel(const float* __restrict__ x,
                                                 float* __restrict__ ws) {
    __shared__ __align__(16) float xt[TT * PADV];
    __shared__ __align__(16) float aS[K_ * V_];
    int tid = threadIdx.x;
    int b = blockIdx.x;
    int tchunk = b & 7;
    int ci = (b >> 3) & 15;
    int n = b >> 7;
    int t0 = tchunk * TT;

    for (int i = tid; i < K_ * V_; i += 256) aS[i] = ws[WS_A + i];

    const float4* xg4 =
        (const float4*)(x + ((long)(n * CIN_ + ci) * T_ + t0) * V_);
    for (int j = tid; j < TT * (V_ / 4); j += 256) {
        float4 v = xg4[j];
        int t = j / (V_ / 4), v4 = (j % (V_ / 4)) * 4;
        *(float4*)(xt + t * PADV + v4) = v;
    }
    __syncthreads();

    int t_local = tid & 63;
    int k = tid >> 6;            // waves 0..2 active, wave 3 idle
    if (k < K_) {
        const float* xr = xt + t_local * PADV;
        const float* ar = aS + k * V_;
        float a0 = 0.f, a1 = 0.f, a2 = 0.f, a3 = 0.f;
        #pragma unroll 5
        for (int v4 = 0; v4 < V_; v4 += 4) {
            float4 xv = *(const float4*)(xr + v4);
            float4 av = *(const float4*)(ar + v4);   // wave-uniform broadcast
            a0 = fmaf(xv.x, av.x, a0);
            a1 = fmaf(xv.y, av.y, a1);
            a2 = fmaf(xv.z, av.z, a2);
            a3 = fmaf(xv.w, av.w, a3);
        }
        float s = (a0 + a1) + (a2 + a3);
        ws[WS_XA + ((long)n * T_ + (t0 + t_local)) * (K_ * CIN_) + k * CIN_ + ci] = s;
    }
}

// ---------------------------------------------------------------------------
// Kernel 3 (fused seq + input-gate GEMM): ONE block per t (512 blocks).
__global__ __launch_bounds__(256) void seqgates_kernel(
    const float* __restrict__ W_gcn, const float* __restrict__ b_gcn,
    const float* __restrict__ W_ih, const float* __restrict__ b_ih,
    const float* __restrict__ b_hh, float* __restrict__ ws) {
    int t = blockIdx.x;
    int tid = threadIdx.x;
    __shared__ float xaS[N_][K_ * CIN_];
    __shared__ __align__(16) float seqS[N_][COUT_];
    __shared__ float saS[K_];

    if (tid < K_) saS[tid] = ws[WS_SA + tid];
    #pragma unroll
    for (int r = 0; r < 3; ++r) {
        int i = tid + r * 256;
        if (i < N_ * K_ * CIN_) {
            int n = i / (K_ * CIN_), kc = i % (K_ * CIN_);
            xaS[n][kc] = ws[WS_XA + (long)(n * T_ + t) * (K_ * CIN_) + kc];
        }
    }
    __syncthreads();

    // Phase 1: thread (n = tid>>4, c0 = (tid&15)*4) computes 4 seq entries.
    {
        int n = tid >> 4, c0 = (tid & 15) * 4;
        #pragma unroll
        for (int cc = 0; cc < 4; ++cc) {
            int c = c0 + cc;
            float s = 0.f;
            #pragma unroll
            for (int k = 0; k < K_; ++k) {
                s = fmaf(b_gcn[k * COUT_ + c], saS[k], s);
                const float* wrow = W_gcn + (long)(k * COUT_ + c) * CIN_;
                #pragma unroll
                for (int ci = 0; ci < CIN_; ++ci)
                    s = fmaf(wrow[ci], xaS[n][k * CIN_ + ci], s);
            }
            seqS[n][c] = s;
        }
    }
    __syncthreads();

    // Phase 2: thread g: 16 accumulators over n; W_ih row streamed as float4.
    {
        int g = tid;
        float acc[N_];
        #pragma unroll
        for (int n = 0; n < N_; ++n) acc[n] = 0.f;
        const float4* wrow4 = (const float4*)(W_ih + (long)g * H_);
        #pragma unroll
        for (int c4 = 0; c4 < H_ / 4; ++c4) {
            float4 w4 = wrow4[c4];
            #pragma unroll
            for (int n = 0; n < N_; ++n) {
                float4 s4 = ((const float4*)seqS[n])[c4];  // LDS broadcast
                acc[n] = fmaf(w4.x, s4.x, acc[n]);
                acc[n] = fmaf(w4.y, s4.y, acc[n]);
                acc[n] = fmaf(w4.z, s4.z, acc[n]);
                acc[n] = fmaf(w4.w, s4.w, acc[n]);
            }
        }
        float bias = b_ih[g] + b_hh[g];
        #pragma unroll
        for (int n = 0; n < N_; ++n)
            ws[WS_XW + (long)(t * N_ + n) * G_ + g] = acc[n] + bias;
    }
}

// ---------------------------------------------------------------------------
// Kernel 4: sequential LSTM scan — R7 structure (measured floor 273us) with
// ONE change: the 16 weight-float4 loads are asm volatile global_load_dwordx4.
// R2-R7/R9 evidence: the compiler treats plain loads as rematerializable and
// sinks them into the step loop (VGPR_Count stuck at 44-56), re-streaming
// 64KB/step from L2/LDS (~1300cy, the measured floor). asm volatile results
// CANNOT be re-executed or sunk -> weights must stay register-resident
// (512-VGPR budget at __launch_bounds__(256,1)). Falsifier: VGPR_Count>=128.
__global__ __launch_bounds__(256, 1) void lstm_kernel(
    const float* __restrict__ W_hh, const float* __restrict__ W_fc,
    const float* __restrict__ b_fc, const float* __restrict__ ws,
    float* __restrict__ out) {
    int n = blockIdx.x;
    int w = threadIdx.x >> 6;     // gate type (torch order: i,f,g,o)
    int lane = threadIdx.x & 63;  // gate index / h index

    // One-time, non-rematerializable load of this thread's W_hh row.
    const f32x4* wr = (const f32x4*)(W_hh + (long)(w * H_ + lane) * H_);
    f32x4 w0, w1, w2, w3, w4, w5, w6, w7, w8, w9, w10, w11, w12, w13, w14, w15;
    #define WLOAD(i) \
        asm volatile("global_load_dwordx4 %0, %1, off" : "=v"(w##i) : "v"(wr + i));
    WLOAD(0)  WLOAD(1)  WLOAD(2)  WLOAD(3)
    WLOAD(4)  WLOAD(5)  WLOAD(6)  WLOAD(7)
    WLOAD(8)  WLOAD(9)  WLOAD(10) WLOAD(11)
    WLOAD(12) WLOAD(13) WLOAD(14) WLOAD(15)
    #undef WLOAD
    asm volatile("s_waitcnt vmcnt(0)" ::: "memory");

    __shared__ __align__(16) float hS[H_];
    __shared__ float gbuf[4][H_];

    if (threadIdx.x < H_) hS[threadIdx.x] = 0.f;
    float ccell = 0.f, hlast = 0.f;   // live only in wave 0
    __syncthreads();

    const float* xw = ws + WS_XW + (long)n * G_ + (w * H_ + lane);
    // depth-2 prefetch of the input-side gate pre-activations
    float x0 = xw[0];
    float x1 = xw[(long)N_ * G_];

    for (int t = 0; t < T_; ++t) {
        float gate = x0;
        x0 = x1;
        if (t + 2 < T_) x1 = xw[(long)(t + 2) * N_ * G_];

        // gate += dot(w*, h) — h via uniform-address ds_read_b128 broadcast
        // (conflict-free), weights in resident VGPRs, 4 accumulators for ILP.
        float a0 = 0.f, a1 = 0.f, a2 = 0.f, a3 = 0.f;
        const float4* h4 = (const float4*)hS;
        #define DOT4(i)                            \
            {                                      \
                float4 hv = h4[i];                 \
                a0 = fmaf(w##i[0], hv.x, a0);      \
                a1 = fmaf(w##i[1], hv.y, a1);      \
                a2 = fmaf(w##i[2], hv.z, a2);      \
                a3 = fmaf(w##i[3], hv.w, a3);      \
            }
        DOT4(0)  DOT4(1)  DOT4(2)  DOT4(3)
        DOT4(4)  DOT4(5)  DOT4(6)  DOT4(7)
        DOT4(8)  DOT4(9)  DOT4(10) DOT4(11)
        DOT4(12) DOT4(13) DOT4(14) DOT4(15)
        #undef DOT4
        gate += (a0 + a1) + (a2 + a3);

        gbuf[w][lane] = gate;
        __syncthreads();               // B1: gates visible
        if (w == 0) {
            float iv = fast_sig(gate);           // own gate == i
            float fv = fast_sig(gbuf[1][lane]);
            float gv = fast_tanh(gbuf[2][lane]);
            float ov = fast_sig(gbuf[3][lane]);
            ccell = fmaf(fv, ccell, iv * gv);
            hlast = ov * fast_tanh(ccell);
            hS[lane] = hlast;
        }
        __syncthreads();               // B2: new h visible
    }

    if (w == 0) {
        float p = hlast * W_fc[lane];
        #pragma unroll
        for (int m = 1; m < 64; m <<= 1) p += __shfl_xor(p, m);
        if (lane == 0) out[n] = p + b_fc[0];
    }
}

// ---------------------------------------------------------------------------
extern "C" void kernel_launch(void* const* d_in, const int* in_sizes, int n_in,
                              void* d_out, int out_size, void* d_ws, size_t ws_size,
                              hipStream_t stream) {
    const float* x     = (const float*)d_in[0];
    const float* A     = (const float*)d_in[1];
    const float* W_gcn = (const float*)d_in[2];
    const float* b_gcn = (const float*)d_in[3];
    const float* W_ih  = (const float*)d_in[4];
    const float* W_hh  = (const float*)d_in[5];
    const float* b_ih  = (const float*)d_in[6];
    const float* b_hh  = (const float*)d_in[7];
    const float* W_fc  = (const float*)d_in[8];
    const float* b_fc  = (const float*)d_in[9];
    float* out = (float*)d_out;
    float* ws  = (float*)d_ws;

    // 1) fused: copy A->out, a[k][v], sa[k]
    prep_kernel<<<NCOPY + K_, 256, 0, stream>>>(A, out, ws);
    // 2) tiled xa (one block per (n, ci, 64-t chunk))
    xa_kernel<<<N_ * CIN_ * (T_ / TT), 256, 0, stream>>>(x, ws);
    // 3) fused seq + input-side gate GEMM (one block per t)
    seqgates_kernel<<<T_, 256, 0, stream>>>(W_gcn, b_gcn, W_ih, b_ih, b_hh, ws);
    // 4) sequential LSTM scan + final FC
    lstm_kernel<<<N_, 256, 0, stream>>>(W_hh, W_fc, b_fc, ws, out);
}